// Round 2
// baseline (273.145 us; speedup 1.0000x reference)
//
#include <hip/hip_runtime.h>

#define BATCH 2
#define C 20
#define H 512
#define W 512
#define NPIX (H*W)        // 262144
#define NW 16
#define NH 16
#define K 256
#define NITERS 10
#define SPLIT 4           // each block handles 8 rows x 32 cols = 256 pixels
#define PITCH 260         // LDS tile pitch (floats), 16B-aligned rows, breaks pow2 stride
#define NEG_INF_F (-1.0e10f)
#define PART_STRIDE 189   // 9 neighbors * (20 ch + 1 den)

// ---------------------------------------------------------------- init spf0
// One wave per (b, k, ch): mean of pf over the 32x32 cell (exactly 1024 px).
__global__ void ssn_init_kernel(const float* __restrict__ x,
                                float* __restrict__ spf0) {
    int bi = blockIdx.x;              // B*K*C
    int ch = bi % C;
    int k  = (bi / C) % K;
    int b  = bi / (C * K);
    int ky = k >> 4, kx = k & 15;
    const float* src = x + ((size_t)(b * C + ch)) * NPIX;
    int l = threadIdx.x;
    float s = 0.f;
#pragma unroll
    for (int i = 0; i < 16; ++i) {
        int p = l + 64 * i;
        int y = ky * 32 + (p >> 5);
        int xx = kx * 32 + (p & 31);
        s += src[y * W + xx];
    }
#pragma unroll
    for (int o = 32; o > 0; o >>= 1) s += __shfl_down(s, o);
    if (l == 0) spf0[(b * K + k) * C + ch] = s * (1.0f / 1024.0f);
}

// ---------------------------------------------------------------- reduce
// part -> normalized spf (one thread per (b,k,ch)). In final mode writes the
// transposed (b,c,k) layout the harness expects for the spf output.
__global__ void ssn_reduce_kernel(const float* __restrict__ part,
                                  float* __restrict__ spf,
                                  float* __restrict__ outSpf,
                                  int final_mode) {
    int idx = blockIdx.x * blockDim.x + threadIdx.x;   // B*K*C
    if (idx >= BATCH * K * C) return;
    int ch = idx % C;
    int k  = (idx / C) % K;
    int b  = idx / (C * K);
    int ky = k >> 4, kx = k & 15;
    float num = 0.f, den = 0.f;
#pragma unroll
    for (int j2 = 0; j2 < 9; ++j2) {
        int cy = ky - (j2 / 3 - 1), cx = kx - (j2 % 3 - 1);
        if (cy >= 0 && cy < NH && cx >= 0 && cx < NW) {
            const float* p = part +
                (size_t)(b * K + cy * NW + cx) * (SPLIT * PART_STRIDE) + j2 * 21;
#pragma unroll
            for (int ss = 0; ss < SPLIT; ++ss) {
                num += p[ss * PART_STRIDE + ch];
                den += p[ss * PART_STRIDE + 20];
            }
        }
    }
    float v = num / fmaxf(den, 1e-8f);
    if (final_mode) outSpf[(b * C + ch) * K + k] = v;
    else            spf[(b * K + k) * C + ch]    = v;
}

// ---------------------------------------------------------------- iterate
// Block = (b, cell, split): 256 pixels. Phase 0: load 9 neighbor spf rows
// (180 floats) + per-neighbor sum-of-squares. Phase A: scores via
// 2*<pf,spf_j> - |spf_j|^2 (softmax shift-invariance drops the |pf|^2 term),
// softmax -> w[9]; stash pf,w tiles in LDS. Phase B: 189 dot-products ->
// dedicated partial slot (no atomics).
__global__ __launch_bounds__(256)
void ssn_iterate_kernel(const float* __restrict__ x,
                        const float* __restrict__ spf,
                        float* __restrict__ wpart,
                        float* __restrict__ outQ,
                        int last) {
    __shared__ float spf_lds[9][C];
    __shared__ float sumsq_lds[9];
    __shared__ float pf_tile[C][PITCH];
    __shared__ float w_tile[9][PITCH];

    int t = threadIdx.x;
    int bi = blockIdx.x;
    int s    = bi & 3;
    int cell = (bi >> 2) & (K - 1);
    int b    = bi >> 10;
    int ky = cell >> 4, kx = cell & 15;

    // ---- phase 0: neighbor spf (+ sumsq) into LDS
    if (t < 9 * C) {
        int jj = t / C, ch = t % C;
        int ny = ky + jj / 3 - 1, nx = kx + jj % 3 - 1;
        float v = 0.f;
        if (ny >= 0 && ny < NH && nx >= 0 && nx < NW)
            v = spf[(size_t)(b * K + ny * NW + nx) * C + ch];
        spf_lds[jj][ch] = v;
    }
    if (t < 9) {
        int ny = ky + t / 3 - 1, nx = kx + t % 3 - 1;
        float ss2 = 0.f;
        if (ny >= 0 && ny < NH && nx >= 0 && nx < NW) {
            const float* sp = spf + (size_t)(b * K + ny * NW + nx) * C;
#pragma unroll
            for (int ch = 0; ch < C; ++ch) ss2 += sp[ch] * sp[ch];
        }
        sumsq_lds[t] = ss2;
    }
    __syncthreads();

    // ---- phase A: per-pixel scores + softmax
    int py = t >> 5, px = t & 31;
    int y  = ky * 32 + s * 8 + py;
    int xx = kx * 32 + px;

    float pf[C];
    const float* xb = x + (size_t)b * C * NPIX + y * W + xx;
#pragma unroll
    for (int ch = 0; ch < C; ++ch) pf[ch] = xb[(size_t)ch * NPIX];

    float sc[9];
#pragma unroll
    for (int j = 0; j < 9; ++j) {
        int ny = ky + j / 3 - 1, nx = kx + j % 3 - 1;
        bool valid = (ny >= 0 && ny < NH && nx >= 0 && nx < NW);
        float dot = 0.f;
#pragma unroll
        for (int ch = 0; ch < C; ++ch) dot = fmaf(pf[ch], spf_lds[j][ch], dot);
        sc[j] = valid ? fmaf(2.f, dot, -sumsq_lds[j]) : NEG_INF_F;
    }
    float m = sc[0];
#pragma unroll
    for (int j = 1; j < 9; ++j) m = fmaxf(m, sc[j]);
    float wv[9], wsum = 0.f;
#pragma unroll
    for (int j = 0; j < 9; ++j) { wv[j] = __expf(sc[j] - m); wsum += wv[j]; }
    float inv = 1.0f / wsum;
#pragma unroll
    for (int j = 0; j < 9; ++j) { wv[j] *= inv; w_tile[j][t] = wv[j]; }
#pragma unroll
    for (int ch = 0; ch < C; ++ch) pf_tile[ch][t] = pf[ch];

    if (last) {
        float* q = outQ + (size_t)b * 9 * NPIX + y * W + xx;
#pragma unroll
        for (int j = 0; j < 9; ++j) q[(size_t)j * NPIX] = wv[j];
    }
    __syncthreads();

    // ---- phase B: 189 dot-products of length 256 from LDS tiles
    if (t < PART_STRIDE) {
        int j = t / 21, r = t % 21;
        const float4* wt = (const float4*)&w_tile[j][0];
        float acc = 0.f;
        if (r < 20) {
            const float4* pt = (const float4*)&pf_tile[r][0];
#pragma unroll 4
            for (int p = 0; p < 64; ++p) {
                float4 w4 = wt[p];
                float4 f4 = pt[p];
                acc += w4.x * f4.x + w4.y * f4.y + w4.z * f4.z + w4.w * f4.w;
            }
        } else {
#pragma unroll 4
            for (int p = 0; p < 64; ++p) {
                float4 w4 = wt[p];
                acc += w4.x + w4.y + w4.z + w4.w;
            }
        }
        wpart[(size_t)(b * K + cell) * (SPLIT * PART_STRIDE)
              + s * PART_STRIDE + t] = acc;
    }
}

// ---------------------------------------------------------------- launch
extern "C" void kernel_launch(void* const* d_in, const int* in_sizes, int n_in,
                              void* d_out, int out_size, void* d_ws, size_t ws_size,
                              hipStream_t stream) {
    const float* x = (const float*)d_in[0];
    float* out = (float*)d_out;
    float* outQ   = out;                                   // B*9*NPIX
    float* outSpf = out + (size_t)BATCH * 9 * NPIX;        // B*C*K
    float* outX   = outSpf + (size_t)BATCH * C * K;        // B*C*NPIX

    float* ws   = (float*)d_ws;
    float* spf  = ws;                                      // B*K*C
    float* part = spf + (size_t)BATCH * K * C;             // B*K*SPLIT*189

    // x passthrough output — plain d2d copy
    hipMemcpyAsync(outX, x, sizeof(float) * (size_t)BATCH * C * NPIX,
                   hipMemcpyDeviceToDevice, stream);

    ssn_init_kernel<<<BATCH * K * C, 64, 0, stream>>>(x, spf);

    for (int it = 0; it < NITERS; ++it) {
        ssn_iterate_kernel<<<BATCH * K * SPLIT, 256, 0, stream>>>(
            x, spf, part, outQ, (it == NITERS - 1) ? 1 : 0);
        if (it < NITERS - 1)
            ssn_reduce_kernel<<<(BATCH * K * C + 255) / 256, 256, 0, stream>>>(
                part, spf, nullptr, 0);
    }
    ssn_reduce_kernel<<<(BATCH * K * C + 255) / 256, 256, 0, stream>>>(
        part, nullptr, outSpf, 1);
}

// Round 3
// 255.514 us; speedup vs baseline: 1.0690x; 1.0690x over previous
//
#include <hip/hip_runtime.h>

#define BATCH 2
#define C 20
#define H 512
#define W 512
#define NPIX (H*W)        // 262144
#define NW 16
#define NH 16
#define K 256
#define NITERS 10
#define SPLIT 4           // each block handles 8 rows x 32 cols = 256 pixels
#define PITCH 260         // LDS tile pitch (floats), breaks pow2 stride
#define NEG_INF_F (-1.0e10f)
#define PART_STRIDE 189   // 9 neighbors * (20 ch + 1 den)

// ---------------------------------------------------------------- init
// Same block shape as iterate: copies x -> outX and emits the cell sums as a
// "uniform weights" partial record (j=4 center, den=256) so the standard
// reduce kernel produces spf0 = cell mean. Kills the separate d2d memcpy.
__global__ __launch_bounds__(256)
void ssn_init_kernel(const float* __restrict__ x,
                     float* __restrict__ outX,
                     float* __restrict__ wpart) {
    __shared__ float pf_tile[C][PITCH];
    __shared__ float chpart[80];
    int t = threadIdx.x;
    int bi = blockIdx.x;
    int s    = bi & 3;
    int cell = (bi >> 2) & (K - 1);
    int b    = bi >> 10;
    int ky = cell >> 4, kx = cell & 15;
    int py = t >> 5, px = t & 31;
    int y  = ky * 32 + s * 8 + py;
    int xx = kx * 32 + px;

    const float* xb = x    + (size_t)b * C * NPIX + y * W + xx;
    float*       ox = outX + (size_t)b * C * NPIX + y * W + xx;
#pragma unroll
    for (int ch = 0; ch < C; ++ch) {
        float v = xb[(size_t)ch * NPIX];
        ox[(size_t)ch * NPIX] = v;
        pf_tile[ch][t] = v;
    }
    __syncthreads();
    if (t < 80) {
        int ch = t >> 2, q = t & 3;
        const float4* p = (const float4*)&pf_tile[ch][0];
        float s4 = 0.f;
#pragma unroll
        for (int i = 0; i < 16; ++i) {
            float4 v = p[q * 16 + i];
            s4 += v.x + v.y + v.z + v.w;
        }
        chpart[t] = s4;
    }
    __syncthreads();
    if (t < PART_STRIDE) {
        float v = 0.f;
        if (t >= 84 && t < 104) {
            int ch = t - 84;
            v = chpart[ch * 4] + chpart[ch * 4 + 1]
              + chpart[ch * 4 + 2] + chpart[ch * 4 + 3];
        } else if (t == 104) {
            v = 256.0f;
        }
        wpart[(size_t)(b * K + cell) * (SPLIT * PART_STRIDE)
              + s * PART_STRIDE + t] = v;
    }
}

// ---------------------------------------------------------------- reduce
// part -> normalized spf (one thread per (b,k,ch)); final mode writes the
// transposed (b,c,k) output layout.
__global__ void ssn_reduce_kernel(const float* __restrict__ part,
                                  float* __restrict__ spf,
                                  float* __restrict__ outSpf,
                                  int final_mode) {
    int idx = blockIdx.x * blockDim.x + threadIdx.x;   // B*K*C
    if (idx >= BATCH * K * C) return;
    int ch = idx % C;
    int k  = (idx / C) % K;
    int b  = idx / (C * K);
    int ky = k >> 4, kx = k & 15;
    float num = 0.f, den = 0.f;
#pragma unroll
    for (int j2 = 0; j2 < 9; ++j2) {
        int cy = ky - (j2 / 3 - 1), cx = kx - (j2 % 3 - 1);
        if (cy >= 0 && cy < NH && cx >= 0 && cx < NW) {
            const float* p = part +
                (size_t)(b * K + cy * NW + cx) * (SPLIT * PART_STRIDE) + j2 * 21;
#pragma unroll
            for (int ss = 0; ss < SPLIT; ++ss) {
                num += p[ss * PART_STRIDE + ch];
                den += p[ss * PART_STRIDE + 20];
            }
        }
    }
    float v = num / fmaxf(den, 1e-8f);
    if (final_mode) outSpf[(b * C + ch) * K + k] = v;
    else            spf[(b * K + k) * C + ch]    = v;
}

// ---------------------------------------------------------------- iterate
__global__ __launch_bounds__(256)
void ssn_iterate_kernel(const float* __restrict__ x,
                        const float* __restrict__ spf,
                        float* __restrict__ wpart,
                        float* __restrict__ outQ,
                        int last) {
    __shared__ float spf_lds[9][C];
    __shared__ float sumsq_lds[9];
    __shared__ float pf_tile[C + 1][PITCH];   // row 20 = all-ones (den column)
    __shared__ float w_tile[9][PITCH];

    int t = threadIdx.x;
    int bi = blockIdx.x;
    int s    = bi & 3;
    int cell = (bi >> 2) & (K - 1);
    int b    = bi >> 10;
    int ky = cell >> 4, kx = cell & 15;

    int py = t >> 5, px = t & 31;
    int y  = ky * 32 + s * 8 + py;
    int xx = kx * 32 + px;

    // ---- hoisted x loads: in flight across phase 0 + barrier
    float pf[C];
    const float* xb = x + (size_t)b * C * NPIX + y * W + xx;
#pragma unroll
    for (int ch = 0; ch < C; ++ch) pf[ch] = xb[(size_t)ch * NPIX];

    // ---- phase 0: neighbor spf (+ sumsq) into LDS
    if (t < 9 * C) {
        int jj = t / C, ch = t % C;
        int ny = ky + jj / 3 - 1, nx = kx + jj % 3 - 1;
        float v = 0.f;
        if (ny >= 0 && ny < NH && nx >= 0 && nx < NW)
            v = spf[(size_t)(b * K + ny * NW + nx) * C + ch];
        spf_lds[jj][ch] = v;
    }
    if (t < 9) {
        int ny = ky + t / 3 - 1, nx = kx + t % 3 - 1;
        float ss2 = 0.f;
        if (ny >= 0 && ny < NH && nx >= 0 && nx < NW) {
            const float* sp = spf + (size_t)(b * K + ny * NW + nx) * C;
#pragma unroll
            for (int ch = 0; ch < C; ++ch) ss2 += sp[ch] * sp[ch];
        }
        sumsq_lds[t] = ss2;
    }
    __syncthreads();

    // ---- phase A: scores via 2<pf,spf_j> - |spf_j|^2 (shift-invariant),
    // softmax -> w; stash pf,w tiles in LDS
    float sc[9];
#pragma unroll
    for (int j = 0; j < 9; ++j) {
        int ny = ky + j / 3 - 1, nx = kx + j % 3 - 1;
        bool valid = (ny >= 0 && ny < NH && nx >= 0 && nx < NW);
        float dot = 0.f;
#pragma unroll
        for (int ch = 0; ch < C; ++ch) dot = fmaf(pf[ch], spf_lds[j][ch], dot);
        sc[j] = valid ? fmaf(2.f, dot, -sumsq_lds[j]) : NEG_INF_F;
    }
    float m = sc[0];
#pragma unroll
    for (int j = 1; j < 9; ++j) m = fmaxf(m, sc[j]);
    float wv[9], wsum = 0.f;
#pragma unroll
    for (int j = 0; j < 9; ++j) { wv[j] = __expf(sc[j] - m); wsum += wv[j]; }
    float inv = 1.0f / wsum;
#pragma unroll
    for (int j = 0; j < 9; ++j) { wv[j] *= inv; w_tile[j][t] = wv[j]; }
#pragma unroll
    for (int ch = 0; ch < C; ++ch) pf_tile[ch][t] = pf[ch];
    pf_tile[C][t] = 1.0f;

    if (last) {
        float* q = outQ + (size_t)b * 9 * NPIX + y * W + xx;
#pragma unroll
        for (int j = 0; j < 9; ++j) q[(size_t)j * NPIX] = wv[j];
    }
    __syncthreads();

    // ---- phase B: 9x21 output register-tiled as 3x3 tiles of (3j x 7r).
    // 144 threads, 16 per tile; each handles 4 float4-chunks (16 px) with
    // 3+7 LDS reads per chunk for 21 partials; 16-lane shfl_down tree.
    if (t < 144) {
        int tile = t >> 4;       // 0..8
        int lane = t & 15;
        int jt = tile / 3;       // j in {3jt..3jt+2}
        int rt = tile % 3;       // r in {7rt..7rt+6}
        float acc[3][7];
#pragma unroll
        for (int jj = 0; jj < 3; ++jj)
#pragma unroll
            for (int rr = 0; rr < 7; ++rr) acc[jj][rr] = 0.f;

#pragma unroll
        for (int cc = 0; cc < 4; ++cc) {
            int c4 = lane + (cc << 4);   // float4 chunk 0..63
            float4 w4[3], f4[7];
#pragma unroll
            for (int jj = 0; jj < 3; ++jj)
                w4[jj] = ((const float4*)&w_tile[3 * jt + jj][0])[c4];
#pragma unroll
            for (int rr = 0; rr < 7; ++rr)
                f4[rr] = ((const float4*)&pf_tile[7 * rt + rr][0])[c4];
#pragma unroll
            for (int jj = 0; jj < 3; ++jj)
#pragma unroll
                for (int rr = 0; rr < 7; ++rr) {
                    acc[jj][rr] = fmaf(w4[jj].x, f4[rr].x, acc[jj][rr]);
                    acc[jj][rr] = fmaf(w4[jj].y, f4[rr].y, acc[jj][rr]);
                    acc[jj][rr] = fmaf(w4[jj].z, f4[rr].z, acc[jj][rr]);
                    acc[jj][rr] = fmaf(w4[jj].w, f4[rr].w, acc[jj][rr]);
                }
        }
        // reduce over the 16 aligned lanes of this tile
#pragma unroll
        for (int off = 8; off >= 1; off >>= 1)
#pragma unroll
            for (int jj = 0; jj < 3; ++jj)
#pragma unroll
                for (int rr = 0; rr < 7; ++rr)
                    acc[jj][rr] += __shfl_down(acc[jj][rr], off);
        if (lane == 0) {
            float* dst = wpart + (size_t)(b * K + cell) * (SPLIT * PART_STRIDE)
                       + s * PART_STRIDE;
#pragma unroll
            for (int jj = 0; jj < 3; ++jj)
#pragma unroll
                for (int rr = 0; rr < 7; ++rr)
                    dst[(3 * jt + jj) * 21 + 7 * rt + rr] = acc[jj][rr];
        }
    }
}

// ---------------------------------------------------------------- launch
extern "C" void kernel_launch(void* const* d_in, const int* in_sizes, int n_in,
                              void* d_out, int out_size, void* d_ws, size_t ws_size,
                              hipStream_t stream) {
    const float* x = (const float*)d_in[0];
    float* out = (float*)d_out;
    float* outQ   = out;                                   // B*9*NPIX
    float* outSpf = out + (size_t)BATCH * 9 * NPIX;        // B*C*K
    float* outX   = outSpf + (size_t)BATCH * C * K;        // B*C*NPIX

    float* ws   = (float*)d_ws;
    float* spf  = ws;                                      // B*K*C
    float* part = spf + (size_t)BATCH * K * C;             // B*K*SPLIT*189

    // init: x->outX copy fused with cell-mean partials (uniform-weight record)
    ssn_init_kernel<<<BATCH * K * SPLIT, 256, 0, stream>>>(x, outX, part);
    ssn_reduce_kernel<<<160, 64, 0, stream>>>(part, spf, nullptr, 0);

    for (int it = 0; it < NITERS; ++it) {
        ssn_iterate_kernel<<<BATCH * K * SPLIT, 256, 0, stream>>>(
            x, spf, part, outQ, (it == NITERS - 1) ? 1 : 0);
        if (it < NITERS - 1)
            ssn_reduce_kernel<<<160, 64, 0, stream>>>(part, spf, nullptr, 0);
    }
    ssn_reduce_kernel<<<160, 64, 0, stream>>>(part, nullptr, outSpf, 1);
}